// Round 14
// baseline (333.946 us; speedup 1.0000x reference)
//
#include <hip/hip_runtime.h>
#include <math.h>

#define Bsz 4
#define Lseq 1024
#define Dm 256
#define Hh 16
#define HDm 16
#define DIm 512
#define Ssz 64
#define DTRm 16
#define NCH (Bsz * DIm)
#define CHK 64
#define NCHK (Lseq / CHK)
#define CHA 16
#define NCA (Lseq / CHA)

typedef __attribute__((ext_vector_type(8))) short s8v;
typedef __attribute__((ext_vector_type(4))) short s4v;
typedef __attribute__((ext_vector_type(4))) float f4v;
typedef unsigned short u16;

static __device__ __forceinline__ float wave_sum(float v) {
    #pragma unroll
    for (int m = 32; m >= 1; m >>= 1) v += __shfl_xor(v, m, 64);
    return v;
}

static __device__ __forceinline__ float bcast(float v, int l) {
    return __uint_as_float(__builtin_amdgcn_readlane(__float_as_uint(v), l));
}

static __device__ __forceinline__ short f2bf(float f) {
    unsigned int u = __float_as_uint(f);
    u = (u + 0x7fffu + ((u >> 16) & 1u)) >> 16;
    return (short)u;
}

static __device__ __forceinline__ float bf2f(u16 u) {
    return __uint_as_float(((unsigned int)u) << 16);
}

static __device__ __forceinline__ s8v pack8(float4 a, float4 b) {
    s8v v;
    v[0] = f2bf(a.x); v[1] = f2bf(a.y); v[2] = f2bf(a.z); v[3] = f2bf(a.w);
    v[4] = f2bf(b.x); v[5] = f2bf(b.y); v[6] = f2bf(b.z); v[7] = f2bf(b.w);
    return v;
}

static __device__ __forceinline__ s4v pack4(float4 a) {
    s4v v;
    v[0] = f2bf(a.x); v[1] = f2bf(a.y); v[2] = f2bf(a.z); v[3] = f2bf(a.w);
    return v;
}

// 64x64 MFMA tile core
static __device__ __forceinline__ void mfma_core(const u16* __restrict__ A, int lda,
                                                 const u16* __restrict__ W, int ldw,
                                                 int m0, int n0, int K,
                                                 u16 (*As)[40], u16 (*Ws)[40],
                                                 f4v acc[2][2], int tid) {
    int wave = tid >> 6, lane = tid & 63;
    int quad = lane >> 4, r = lane & 15;
    int mo = (wave >> 1) * 32, no = (wave & 1) * 32;
    for (int k0 = 0; k0 < K; k0 += 32) {
        {
            int m = tid >> 2, kk = (tid & 3) * 8;
            *(s8v*)&As[m][kk] = *(const s8v*)(A + (size_t)(m0 + m) * lda + k0 + kk);
        }
        {
            int n = tid >> 2, kk = (tid & 3) * 8;
            *(s8v*)&Ws[n][kk] = *(const s8v*)(W + (size_t)(n0 + n) * ldw + k0 + kk);
        }
        __syncthreads();
        s8v af[2], bf[2];
        #pragma unroll
        for (int i = 0; i < 2; i++) af[i] = *(const s8v*)&As[mo + i * 16 + r][quad * 8];
        #pragma unroll
        for (int j = 0; j < 2; j++) bf[j] = *(const s8v*)&Ws[no + j * 16 + r][quad * 8];
        #pragma unroll
        for (int i = 0; i < 2; i++)
            #pragma unroll
            for (int j = 0; j < 2; j++)
                acc[i][j] = __builtin_amdgcn_mfma_f32_16x16x32_bf16(af[i], bf[j], acc[i][j], 0, 0, 0);
        __syncthreads();
    }
}

// wbf offsets (u16 elements)
#define WB_INPJ 0
#define WB_K    262144
#define WB_V    327680
#define WB_MQ   393216
#define WB_FUSE 655360
#define WB_XP   917504
#define WB_OUT  991232
#define WB_O    1122304
#define WB_GATE 1187840
#define WB_OUTT 1318912
#define WB_WDT  1449984
#define WB_W1P  1712128
#define WB_OT   1843200
#define WB_W2P  1908736

// ---- ln_pool: LN+pools (0-511) + wcvt (512-1155) + Wdt (1156-1411) + out_wT (1412-1475)
//      + o_wT (1476-1507) + c2 (1508) ----
__global__ __launch_bounds__(256) void ln_pool(const float* __restrict__ x,
                                               const float* __restrict__ g,
                                               const float* __restrict__ bb,
                                               u16* __restrict__ xnb, u16* __restrict__ xd2b,
                                               u16* __restrict__ xd4b, u16* __restrict__ xd8b,
                                               const float* __restrict__ in_proj_w,
                                               const float* __restrict__ k_w,
                                               const float* __restrict__ v_w,
                                               const float* __restrict__ mq_w,
                                               const float* __restrict__ fuse_w,
                                               const float* __restrict__ x_proj_w,
                                               const float* __restrict__ out_w,
                                               const float* __restrict__ o_w,
                                               const float* __restrict__ gate_w,
                                               const float* __restrict__ dt_w,
                                               const float* __restrict__ o_b,
                                               u16* __restrict__ wbf,
                                               float* __restrict__ c2) {
    int bx = blockIdx.x;
    int tid = threadIdx.x;
    if (bx < 512) {
        __shared__ float p2[4][256];
        int wid = tid >> 6, lane = tid & 63;
        int gr0 = bx * 8;
        int b = gr0 >> 10, t0 = gr0 & 1023;
        float4 g4 = *(const float4*)(g + lane * 4);
        float4 b4 = *(const float4*)(bb + lane * 4);
        float4 res[2];
        #pragma unroll
        for (int rr = 0; rr < 2; rr++) {
            int row = gr0 + wid * 2 + rr;
            float4 xv = *(const float4*)(x + (size_t)row * 256 + lane * 4);
            float s = wave_sum(xv.x + xv.y + xv.z + xv.w);
            float mean = s * (1.0f / 256.0f);
            float d0 = xv.x - mean, d1 = xv.y - mean, d2 = xv.z - mean, d3 = xv.w - mean;
            float s2 = wave_sum(d0 * d0 + d1 * d1 + d2 * d2 + d3 * d3);
            float inv = rsqrtf(s2 * (1.0f / 256.0f) + 1e-5f);
            float4 r;
            r.x = d0 * inv * g4.x + b4.x; r.y = d1 * inv * g4.y + b4.y;
            r.z = d2 * inv * g4.z + b4.z; r.w = d3 * inv * g4.w + b4.w;
            *(s4v*)(xnb + (size_t)row * 256 + lane * 4) = pack4(r);
            res[rr] = r;
        }
        float4 a2;
        a2.x = 0.5f * (res[0].x + res[1].x); a2.y = 0.5f * (res[0].y + res[1].y);
        a2.z = 0.5f * (res[0].z + res[1].z); a2.w = 0.5f * (res[0].w + res[1].w);
        *(s4v*)(xd2b + (size_t)(b * 512 + (t0 >> 1) + wid) * 256 + lane * 4) = pack4(a2);
        *(float4*)&p2[wid][lane * 4] = a2;
        __syncthreads();
        if (wid < 2) {
            float4 u = *(const float4*)&p2[2 * wid][lane * 4];
            float4 w = *(const float4*)&p2[2 * wid + 1][lane * 4];
            float4 m;
            m.x = 0.5f * (u.x + w.x); m.y = 0.5f * (u.y + w.y);
            m.z = 0.5f * (u.z + w.z); m.w = 0.5f * (u.w + w.w);
            *(s4v*)(xd4b + (size_t)(b * 256 + (t0 >> 2) + wid) * 256 + lane * 4) = pack4(m);
        } else if (wid == 2) {
            float4 q0 = *(const float4*)&p2[0][lane * 4];
            float4 q1 = *(const float4*)&p2[1][lane * 4];
            float4 q2 = *(const float4*)&p2[2][lane * 4];
            float4 q3 = *(const float4*)&p2[3][lane * 4];
            float4 m;
            m.x = 0.25f * ((q0.x + q1.x) + (q2.x + q3.x));
            m.y = 0.25f * ((q0.y + q1.y) + (q2.y + q3.y));
            m.z = 0.25f * ((q0.z + q1.z) + (q2.z + q3.z));
            m.w = 0.25f * ((q0.w + q1.w) + (q2.w + q3.w));
            *(s4v*)(xd8b + (size_t)(b * 128 + (t0 >> 3)) * 256 + lane * 4) = pack4(m);
        }
    } else if (bx < 1156) {
        int l = bx - 512;
        const float* src; u16* dst; int base;
        if (l < 128)      { src = in_proj_w; dst = wbf + WB_INPJ; base = l; }
        else if (l < 160) { src = k_w;      dst = wbf + WB_K;    base = l - 128; }
        else if (l < 192) { src = v_w;      dst = wbf + WB_V;    base = l - 160; }
        else if (l < 320) { src = mq_w;     dst = wbf + WB_MQ;   base = l - 192; }
        else if (l < 448) { src = fuse_w;   dst = wbf + WB_FUSE; base = l - 320; }
        else if (l < 484) { src = x_proj_w; dst = wbf + WB_XP;   base = l - 448; }
        else if (l < 548) { src = out_w;    dst = wbf + WB_OUT;  base = l - 484; }
        else if (l < 580) { src = o_w;      dst = wbf + WB_O;    base = l - 548; }
        else              { src = gate_w;   dst = wbf + WB_GATE; base = l - 580; }
        int idx = base * 2048 + tid * 8;
        const float* sp = src + idx;
        *(s8v*)(dst + idx) = pack8(*(const float4*)sp, *(const float4*)(sp + 4));
    } else if (bx < 1412) {
        // Wdt[n][d] = sum_{k<16} dt_w[n][k] * x_proj_w[k][d]
        int l = bx - 1156;
        int gid = l * 1024 + tid * 4;
        int n = gid >> 9, d0 = gid & 511;
        float4 acc = {0.f, 0.f, 0.f, 0.f};
        #pragma unroll
        for (int k = 0; k < 16; k++) {
            float wv = dt_w[n * 16 + k];
            float4 xp = *(const float4*)(x_proj_w + (size_t)k * 512 + d0);
            acc.x = fmaf(wv, xp.x, acc.x); acc.y = fmaf(wv, xp.y, acc.y);
            acc.z = fmaf(wv, xp.z, acc.z); acc.w = fmaf(wv, xp.w, acc.w);
        }
        *(s4v*)(wbf + WB_WDT + (size_t)n * 512 + d0) = pack4(acc);
    } else if (bx < 1476) {
        // out_wT[d][k] = out_w[k][d]
        int l = bx - 1412;
        int gid = l * 2048 + tid * 8;
        int k = gid >> 9, d0 = gid & 511;
        float4 a0 = *(const float4*)(out_w + (size_t)k * 512 + d0);
        float4 a1 = *(const float4*)(out_w + (size_t)k * 512 + d0 + 4);
        float vv[8] = {a0.x, a0.y, a0.z, a0.w, a1.x, a1.y, a1.z, a1.w};
        #pragma unroll
        for (int i = 0; i < 8; i++)
            wbf[WB_OUTT + (size_t)(d0 + i) * 256 + k] = (u16)f2bf(vv[i]);
    } else if (bx < 1508) {
        // o_wT[k][d] = o_w[d][k]
        int l = bx - 1476;
        int gid = l * 2048 + tid * 8;
        int d = gid >> 8, k0 = gid & 255;
        float4 a0 = *(const float4*)(o_w + (size_t)d * 256 + k0);
        float4 a1 = *(const float4*)(o_w + (size_t)d * 256 + k0 + 4);
        float vv[8] = {a0.x, a0.y, a0.z, a0.w, a1.x, a1.y, a1.z, a1.w};
        #pragma unroll
        for (int i = 0; i < 8; i++)
            wbf[WB_OT + (size_t)(k0 + i) * 256 + d] = (u16)f2bf(vv[i]);
    } else {
        // c2[n] = sum_d gate_w[n][256+d] * o_b[d]
        float s = 0.0f;
        const float* gw = gate_w + (size_t)tid * 512 + 256;
        for (int d = 0; d < 256; d++) s = fmaf(gw[d], o_b[d], s);
        c2[tid] = s;
    }
}

// ======= proj8: xm, zT(swapped), k, v, q0, qd2/4/8, W1', W2' — 2064 blocks =======
__global__ __launch_bounds__(256) void proj8(const u16* __restrict__ xnb,
                                             const u16* __restrict__ xd2b,
                                             const u16* __restrict__ xd4b,
                                             const u16* __restrict__ xd8b,
                                             u16* __restrict__ wbf,
                                             const float* __restrict__ k_b,
                                             const float* __restrict__ v_b,
                                             const float* __restrict__ mq_b,
                                             u16* __restrict__ xmb, float* __restrict__ zT,
                                             float* __restrict__ kmat, float* __restrict__ vmat,
                                             u16* __restrict__ q0b, u16* __restrict__ qd2b,
                                             u16* __restrict__ qd4b, u16* __restrict__ qd8b) {
    __shared__ u16 As[64][40];
    __shared__ u16 Ws[64][40];
    int bx = blockIdx.x;
    int tid = threadIdx.x;
    const u16* A; const u16* W; const float* bias;
    float* Cf = nullptr; u16* Cb = nullptr;
    int lda, ldw, ldc, K = 256, n0, m0;
    if (bx < 512) {
        A = xnb; lda = 256; W = wbf + WB_INPJ; ldw = 256; bias = nullptr; Cb = xmb; ldc = DIm;
        n0 = (bx & 7) * 64; m0 = (bx >> 3) * 64;
    } else if (bx < 1024) {
        int l = bx - 512;
        A = wbf + WB_INPJ + 131072; lda = 256; W = xnb; ldw = 256; bias = nullptr;
        Cf = zT; ldc = 4096;
        m0 = (l >> 6) * 64; n0 = (l & 63) * 64;
    } else if (bx < 1280) {
        int l = bx - 1024;
        A = xnb; lda = 256; W = wbf + WB_K; ldw = 256; bias = k_b; Cf = kmat; ldc = Dm;
        n0 = (l & 3) * 64; m0 = (l >> 2) * 64;
    } else if (bx < 1536) {
        int l = bx - 1280;
        A = xnb; lda = 256; W = wbf + WB_V; ldw = 256; bias = v_b; Cf = vmat; ldc = Dm;
        n0 = (l & 3) * 64; m0 = (l >> 2) * 64;
    } else if (bx < 1792) {
        int l = bx - 1536;
        A = xnb; lda = 256; W = wbf + WB_MQ; ldw = 256; bias = mq_b; Cb = q0b; ldc = Dm;
        n0 = (l & 3) * 64; m0 = (l >> 2) * 64;
    } else if (bx < 1920) {
        int l = bx - 1792;
        A = xd2b; lda = 256; W = wbf + WB_MQ + 65536; ldw = 256; bias = mq_b + 256; Cb = qd2b; ldc = Dm;
        n0 = (l & 3) * 64; m0 = (l >> 2) * 64;
    } else if (bx < 1984) {
        int l = bx - 1920;
        A = xd4b; lda = 256; W = wbf + WB_MQ + 131072; ldw = 256; bias = mq_b + 512; Cb = qd4b; ldc = Dm;
        n0 = (l & 3) * 64; m0 = (l >> 2) * 64;
    } else if (bx < 2016) {
        int l = bx - 1984;
        A = xd8b; lda = 256; W = wbf + WB_MQ + 196608; ldw = 256; bias = mq_b + 768; Cb = qd8b; ldc = Dm;
        n0 = (l & 3) * 64; m0 = (l >> 2) * 64;
    } else if (bx < 2048) {
        int l = bx - 2016;
        A = wbf + WB_GATE; lda = 512; W = wbf + WB_OUTT; ldw = 256; bias = nullptr;
        Cb = wbf + WB_W1P; ldc = 512;
        m0 = (l >> 3) * 64; n0 = (l & 7) * 64;
    } else {
        int l = bx - 2048;
        A = wbf + WB_GATE + 256; lda = 512; W = wbf + WB_OT; ldw = 256; bias = nullptr;
        Cb = wbf + WB_W2P; ldc = 256;
        m0 = (l >> 2) * 64; n0 = (l & 3) * 64;
    }
    f4v acc[2][2];
    #pragma unroll
    for (int i = 0; i < 2; i++)
        #pragma unroll
        for (int j = 0; j < 2; j++) acc[i][j] = (f4v){0.f, 0.f, 0.f, 0.f};
    mfma_core(A, lda, W, ldw, m0, n0, K, As, Ws, acc, tid);
    int wave = tid >> 6, lane = tid & 63;
    int quad = lane >> 4, r = lane & 15;
    int mo = (wave >> 1) * 32, no = (wave & 1) * 32;
    #pragma unroll
    for (int i = 0; i < 2; i++)
        #pragma unroll
        for (int j = 0; j < 2; j++)
            #pragma unroll
            for (int reg = 0; reg < 4; reg++) {
                int m = m0 + mo + i * 16 + quad * 4 + reg;
                int n = n0 + no + j * 16 + r;
                float v = acc[i][j][reg];
                if (bias) v += bias[n];
                if (Cb) Cb[(size_t)m * ldc + n] = (u16)f2bf(v);
                else Cf[(size_t)m * ldc + n] = v;
            }
}

// ======= mid2: fuse GEMM (0-255, on-the-fly interp) + conv+SiLU (256-767) =======
__global__ __launch_bounds__(256) void mid2(const u16* __restrict__ q0b,
                                            const u16* __restrict__ qd2b,
                                            const u16* __restrict__ qd4b,
                                            const u16* __restrict__ qd8b,
                                            const u16* __restrict__ w_fuse,
                                            const float* __restrict__ fuse_b,
                                            float* __restrict__ qbuf,
                                            const u16* __restrict__ xmb,
                                            const float* __restrict__ cw,
                                            const float* __restrict__ cb,
                                            u16* __restrict__ xcb, float* __restrict__ xcT) {
    __shared__ __align__(16) char smem[16640];
    int bx = blockIdx.x;
    int tid = threadIdx.x;
    if (bx < 256) {
        u16 (*As)[40] = (u16(*)[40])smem;
        u16 (*Ws)[40] = (u16(*)[40])(smem + 5120);
        int wave = tid >> 6, lane = tid & 63;
        int quad = lane >> 4, r = lane & 15;
        int n0 = (bx & 3) * 64, m0 = (bx >> 2) * 64;
        int mo = (wave >> 1) * 32, no = (wave & 1) * 32;
        f4v acc[2][2];
        #pragma unroll
        for (int i = 0; i < 2; i++)
            #pragma unroll
            for (int j = 0; j < 2; j++) acc[i][j] = (f4v){0.f, 0.f, 0.f, 0.f};
        for (int k0 = 0; k0 < 1024; k0 += 32) {
            {
                int m = tid >> 2, kk = (tid & 3) * 8;
                int kg = k0 + kk;
                int seg = kg >> 8, dcol = kg & 255;
                int mg = m0 + m;
                s8v pv;
                if (seg == 0) {
                    pv = *(const s8v*)(q0b + (size_t)mg * 256 + dcol);
                } else {
                    int t = mg & 1023, b = mg >> 10;
                    int Lin = 512 >> (seg - 1);
                    const u16* qd = (seg == 1) ? qd2b : (seg == 2) ? qd4b : qd8b;
                    float pos = (t + 0.5f) * ((float)Lin / 1024.0f) - 0.5f;
                    pos = fminf(fmaxf(pos, 0.0f), (float)(Lin - 1));
                    int lo = (int)floorf(pos);
                    int hi = min(lo + 1, Lin - 1);
                    float w = pos - (float)lo;
                    s8v lv = *(const s8v*)(qd + ((size_t)(b * Lin + lo)) * 256 + dcol);
                    s8v hv = *(const s8v*)(qd + ((size_t)(b * Lin + hi)) * 256 + dcol);
                    #pragma unroll
                    for (int i = 0; i < 8; i++) {
                        float lf = bf2f((u16)lv[i]), hf = bf2f((u16)hv[i]);
                        pv[i] = f2bf(lf + w * (hf - lf));
                    }
                }
                *(s8v*)&As[m][kk] = pv;
            }
            {
                int n = tid >> 2, kk = (tid & 3) * 8;
                *(s8v*)&Ws[n][kk] = *(const s8v*)(w_fuse + (size_t)(n0 + n) * 1024 + k0 + kk);
            }
            __syncthreads();
            s8v af[2], bf[2];
            #pragma unroll
            for (int i = 0; i < 2; i++) af[i] = *(const s8v*)&As[mo + i * 16 + r][quad * 8];
            #pragma unroll
            for (int j = 0; j < 2; j++) bf[j] = *(const s8v*)&Ws[no + j * 16 + r][quad * 8];
            #pragma unroll
            for (int i = 0; i < 2; i++)
                #pragma unroll
                for (int j = 0; j < 2; j++)
                    acc[i][j] = __builtin_amdgcn_mfma_f32_16x16x32_bf16(af[i], bf[j], acc[i][j], 0, 0, 0);
            __syncthreads();
        }
        #pragma unroll
        for (int i = 0; i < 2; i++)
            #pragma unroll
            for (int j = 0; j < 2; j++)
                #pragma unroll
                for (int reg = 0; reg < 4; reg++) {
                    int m = m0 + mo + i * 16 + quad * 4 + reg;
                    int n = n0 + no + j * 16 + r;
                    qbuf[(size_t)m * 256 + n] = acc[i][j][reg] + fuse_b[n];
                }
    } else {
        float (*tile)[65] = (float(*)[65])smem;
        int blk = bx - 256;
        int cblk = blk & 7;
        int tblk = (blk >> 3) & 15;
        int b = blk >> 7;
        int c0 = cblk * 64, t0 = tblk * 64;
        int cc = tid & 63;
        int tw = tid >> 6;
        int c = c0 + cc;
        float w0 = cw[c * 4 + 0], w1 = cw[c * 4 + 1], w2 = cw[c * 4 + 2], w3 = cw[c * 4 + 3];
        float bias = cb[c];
        #pragma unroll 4
        for (int i = 0; i < 16; i++) {
            int tl = tw * 16 + i;
            int t = t0 + tl;
            const u16* base = xmb + ((size_t)(b * Lseq + t)) * DIm + c;
            float acc = bias + bf2f(base[0]) * w3;
            if (t >= 3) {
                acc += bf2f(base[-3 * DIm]) * w0 + bf2f(base[-2 * DIm]) * w1 + bf2f(base[-1 * DIm]) * w2;
            } else {
                if (t >= 1) acc += bf2f(base[-1 * DIm]) * w2;
                if (t >= 2) acc += bf2f(base[-2 * DIm]) * w1;
            }
            float r = acc / (1.0f + __expf(-acc));
            xcb[((size_t)(b * Lseq + t)) * DIm + c] = (u16)f2bf(r);
            tile[tl][cc] = r;
        }
        __syncthreads();
        int tcol = tid & 63;
        int crow0 = tid >> 6;
        #pragma unroll 4
        for (int j = 0; j < 16; j++) {
            int crow = crow0 * 16 + j;
            xcT[((size_t)(c0 + crow)) * (Bsz * Lseq) + b * Lseq + t0 + tcol] = tile[tcol][crow];
        }
    }
}

// ======= xproj_ap1: BC-GEMM (0-127, INTERLEAVED dbc2) + dt-GEMM (128-639) + attn pass1 (640-1663) =======
__global__ __launch_bounds__(256) void xproj_ap1(const u16* __restrict__ xcb,
                                                 const u16* __restrict__ wbf,
                                                 float* __restrict__ dbc2,
                                                 const float* __restrict__ dt_b,
                                                 float* __restrict__ dtmT,
                                                 const float* __restrict__ kmat,
                                                 const float* __restrict__ vmat,
                                                 const float* __restrict__ log_tau,
                                                 float* __restrict__ loc) {
    __shared__ __align__(16) char smem[10240];
    int bx = blockIdx.x;
    int tid = threadIdx.x;
    int wid = tid >> 6, lane = tid & 63;
    if (bx < 640) {
        u16 (*As)[40] = (u16(*)[40])smem;
        u16 (*Ws)[40] = (u16(*)[40])(smem + 5120);
        const u16* A; const u16* W;
        int lda, ldw, K, m0, n0, mode;
        if (bx < 128) {
            A = xcb; lda = 512; W = wbf + WB_XP + 16 * 512; ldw = 512; K = 512;
            n0 = (bx & 1) * 64; m0 = (bx >> 1) * 64; mode = 0;
        } else {
            int l = bx - 128;
            A = wbf + WB_WDT; lda = 512; W = xcb; ldw = 512; K = 512;
            m0 = (l >> 6) * 64; n0 = (l & 63) * 64; mode = 1;
        }
        f4v acc[2][2];
        #pragma unroll
        for (int i = 0; i < 2; i++)
            #pragma unroll
            for (int j = 0; j < 2; j++) acc[i][j] = (f4v){0.f, 0.f, 0.f, 0.f};
        mfma_core(A, lda, W, ldw, m0, n0, K, As, Ws, acc, tid);
        int quad = lane >> 4, r = lane & 15;
        int mo = (wid >> 1) * 32, no = (wid & 1) * 32;
        #pragma unroll
        for (int i = 0; i < 2; i++)
            #pragma unroll
            for (int j = 0; j < 2; j++)
                #pragma unroll
                for (int reg = 0; reg < 4; reg++) {
                    int m = m0 + mo + i * 16 + quad * 4 + reg;
                    int n = n0 + no + j * 16 + r;
                    float v = acc[i][j][reg];
                    if (mode == 0) {
                        // interleave: B(state s) -> 2s, C(state s) -> 2s+1
                        int ni = (n < 64) ? (2 * n) : (2 * (n - 64) + 1);
                        dbc2[(size_t)m * 144 + ni] = v;
                    } else {
                        v += dt_b[m];
                        v = fmaxf(v, 0.0f) + log1pf(__expf(-fabsf(v)));
                        dtmT[(size_t)m * 4096 + n] = v;
                    }
                }
    } else {
        float (*Ksh)[CHA][20] = (float(*)[CHA][20])smem;
        float (*Vsh)[CHA][16] = (float(*)[CHA][16])(smem + 5120);
        int wv = (bx - 640) * 4 + wid;
        int bh = wv >> 6, c = wv & 63;
        int b = bh >> 4, h = bh & 15;
        float inv_tau = __expf(-log_tau[h]);
        float rdec = __expf(-inv_tau);
        int t0 = c * CHA;
        int row = lane >> 2, q4 = (lane & 3) * 4;
        const float* kp = kmat + ((size_t)(b * Lseq + t0 + row)) * Dm + h * HDm + q4;
        const float* vp = vmat + ((size_t)(b * Lseq + t0 + row)) * Dm + h * HDm + q4;
        *(float4*)&Ksh[wid][row][q4] = *(const float4*)kp;
        *(float4*)&Vsh[wid][row][q4] = *(const float4*)vp;
        int g = lane >> 4, cc = lane & 15;
        float4 U = {0.f, 0.f, 0.f, 0.f}, T = {0.f, 0.f, 0.f, 0.f};
        #pragma unroll
        for (int s = 0; s < CHA; s++) {
            float4 kf = *(const float4*)&Ksh[wid][s][4 * g];
            float vv = Vsh[wid][s][cc];
            float u0 = kf.x * vv, u1 = kf.y * vv, u2 = kf.z * vv, u3 = kf.w * vv;
            U.x += u0; U.y += u1; U.z += u2; U.w += u3;
            T.x = fmaf(rdec, T.x, u0); T.y = fmaf(rdec, T.y, u1);
            T.z = fmaf(rdec, T.z, u2); T.w = fmaf(rdec, T.w, u3);
        }
        float* op = loc + ((size_t)bh * NCA + c) * 512;
        *(float4*)(op + lane * 4) = U;
        *(float4*)(op + 256 + lane * 4) = T;
    }
}

// ======= sp1_ap2: scan pass1 (0-8191, interleaved B) + attn pass2 in-place (8192-8255) =======
__global__ __launch_bounds__(256) void sp1_ap2(const float* __restrict__ xcT,
                                               const float* __restrict__ dtmT,
                                               const float* __restrict__ dbc2,
                                               const float* __restrict__ A_log,
                                               float* __restrict__ hloc,
                                               float* __restrict__ Pc,
                                               float* __restrict__ loc,
                                               const float* __restrict__ log_tau,
                                               float* __restrict__ kvtot) {
    int bx = blockIdx.x;
    int tid = threadIdx.x;
    int wid = tid >> 6, lane = tid & 63;
    if (bx < 8192) {
        int wave = bx * 4 + wid;
        int ch = wave & (NCH - 1);
        int c  = wave >> 11;
        int b = ch >> 9, d = ch & (DIm - 1);
        float As = -__expf(A_log[d * Ssz + lane]);
        int base_m = b * Lseq + c * CHK;
        float dt_vec = dtmT[(size_t)d * (Bsz * Lseq) + base_m + lane];
        float x_vec  = xcT [(size_t)d * (Bsz * Lseq) + base_m + lane];
        float ux = dt_vec * x_vec;
        float S = dt_vec;
        #pragma unroll
        for (int m = 1; m < 64; m <<= 1) {
            float o = __shfl_up(S, m, 64);
            if (lane >= m) S += o;
        }
        float Stot = bcast(S, 63);
        const float* Bp = dbc2 + (size_t)base_m * 144 + 2 * lane;   // interleaved: B at even
        float h0 = 0.f, h1 = 0.f, h2 = 0.f, h3 = 0.f;
        #pragma unroll 4
        for (int t = 0; t < CHK; t += 4) {
            float B0 = Bp[0], B1 = Bp[144], B2 = Bp[288], B3 = Bp[432];
            Bp += 576;
            float w0 = __expf(As * (Stot - bcast(S, t)))     * bcast(ux, t);
            float w1 = __expf(As * (Stot - bcast(S, t + 1))) * bcast(ux, t + 1);
            float w2 = __expf(As * (Stot - bcast(S, t + 2))) * bcast(ux, t + 2);
            float w3 = __expf(As * (Stot - bcast(S, t + 3))) * bcast(ux, t + 3);
            h0 = fmaf(w0, B0, h0); h1 = fmaf(w1, B1, h1);
            h2 = fmaf(w2, B2, h2); h3 = fmaf(w3, B3, h3);
        }
        size_t o = ((size_t)ch * NCHK + c) * Ssz + lane;
        hloc[o] = (h0 + h1) + (h2 + h3);
        Pc[o] = __expf(As * Stot);
    } else {
        int bh = bx - 8192, e = tid;
        float inv_tau = __expf(-log_tau[bh & 15]);
        float rp = __expf(-(float)CHA * inv_tau);
        float* lp = loc + (size_t)bh * NCA * 512;
        float Ua = 0.f, Ta = 0.f;
        #pragma unroll 8
        for (int c = 0; c < NCA; c++) {
            float tu = lp[c * 512 + e];
            lp[c * 512 + e] = Ua;
            Ua += tu;
            float tt = lp[c * 512 + 256 + e];
            lp[c * 512 + 256 + e] = Ta;
            Ta = fmaf(rp, Ta, tt);
        }
        kvtot[bh * 256 + e] = Ua;
    }
}

// ======= comb_ap3: in-place chunk combine (0-511) + attn pass3 (512-1535) =======
__global__ __launch_bounds__(256) void comb_ap3(float* __restrict__ hloc,
                                                const float* __restrict__ Pc,
                                                const float* __restrict__ q,
                                                const float* __restrict__ kmat,
                                                const float* __restrict__ vmat,
                                                const float* __restrict__ log_tau,
                                                const float* __restrict__ init,
                                                const float* __restrict__ kvtot,
                                                u16* __restrict__ attnb) {
    __shared__ __align__(16) char smem[18432];
    int bx = blockIdx.x;
    int tid = threadIdx.x;
    int wid = tid >> 6, lane = tid & 63;
    if (bx < 512) {
        int wave = bx * 4 + wid;
        size_t base = (size_t)wave * NCHK * Ssz + lane;
        float H = 0.0f;
        #pragma unroll
        for (int c = 0; c < NCHK; c++) {
            size_t o = base + (size_t)c * Ssz;
            float p = Pc[o];
            float hl = hloc[o];
            hloc[o] = H;
            H = fmaf(p, H, hl);
        }
    } else {
        float (*Ksh)[CHA][20] = (float(*)[CHA][20])smem;
        float (*Qsh)[CHA][20] = (float(*)[CHA][20])(smem + 5120);
        float (*Vsh)[CHA][16] = (float(*)[CHA][16])(smem + 10240);
        float (*Ysh)[CHA][16] = (float(*)[CHA][16])(smem + 14336);
        int wv = (bx - 512) * 4 + wid;
        int bh = wv >> 6, c = wv & 63;
        int b = bh >> 4, h = bh & 15;
        float inv_tau = __expf(-log_tau[h]);
        float rdec = __expf(-inv_tau);
        int t0 = c * CHA;
        int row = lane >> 2, q4 = (lane & 3) * 4;
        const float* kp = kmat + ((size_t)(b * Lseq + t0 + row)) * Dm + h * HDm + q4;
        const float* vp = vmat + ((size_t)(b * Lseq + t0 + row)) * Dm + h * HDm + q4;
        const float* qp = q    + ((size_t)(b * Lseq + t0 + row)) * Dm + h * HDm + q4;
        *(float4*)&Ksh[wid][row][q4] = *(const float4*)kp;
        *(float4*)&Vsh[wid][row][q4] = *(const float4*)vp;
        *(float4*)&Qsh[wid][row][q4] = *(const float4*)qp;
        int g = lane >> 4, cc = lane & 15;
        size_t ibase = ((size_t)bh * NCA + c) * 512;
        float4 U  = *(const float4*)(init + ibase + lane * 4);
        float4 T  = *(const float4*)(init + ibase + 256 + lane * 4);
        float4 KV = *(const float4*)(kvtot + bh * 256 + lane * 4);
        float om = 1.0f - rdec;
        float geom = (om > 1e-8f) ? (1.0f - __expf(-inv_tau * (float)t0)) / om : (float)t0;
        #pragma unroll
        for (int s = 0; s < CHA; s++) {
            int i = t0 + s;
            geom = fmaf(geom, rdec, 1.0f);
            float4 kf = *(const float4*)&Ksh[wid][s][4 * g];
            float4 qf = *(const float4*)&Qsh[wid][s][4 * g];
            float vv = Vsh[wid][s][cc];
            float u0 = kf.x * vv, u1 = kf.y * vv, u2 = kf.z * vv, u3 = kf.w * vv;
            U.x += u0; U.y += u1; U.z += u2; U.w += u3;
            T.x = fmaf(rdec, T.x, u0); T.y = fmaf(rdec, T.y, u1);
            T.z = fmaf(rdec, T.z, u2); T.w = fmaf(rdec, T.w, u3);
            float p;
            p = qf.x * (KV.x - U.x + T.x);
            p = fmaf(qf.y, KV.y - U.y + T.y, p);
            p = fmaf(qf.z, KV.z - U.z + T.z, p);
            p = fmaf(qf.w, KV.w - U.w + T.w, p);
            p += __shfl_xor(p, 16, 64);
            p += __shfl_xor(p, 32, 64);
            float deno = fmaxf((float)(Lseq - 1 - i) + geom, 1e-6f);
            float yv = p * (0.25f / deno);
            if (lane < 16) Ysh[wid][s][lane] = yv;
        }
        float4 yv4 = *(const float4*)&Ysh[wid][row][q4];
        *(s4v*)(attnb + ((size_t)(b * Lseq + t0 + row)) * Dm + h * HDm + q4) = pack4(yv4);
    }
}

// ======= scan_pass3: standalone, __expf, INTERLEAVED B/C (one dwordx2 per step) =======
__global__ __launch_bounds__(256) void scan_pass3(const float* __restrict__ xcT,
                                                  const float* __restrict__ dtmT,
                                                  const float* __restrict__ zT,
                                                  const float* __restrict__ dbc2,
                                                  const float* __restrict__ A_log,
                                                  const float* __restrict__ D_ssm,
                                                  const float* __restrict__ Hinit,
                                                  u16* __restrict__ yTb) {
    __shared__ float hCs[4][16][68];
    int wid = threadIdx.x >> 6;
    int lane = threadIdx.x & 63;
    int wave = blockIdx.x * 4 + wid;
    int ch = wave & (NCH - 1);
    int c  = wave >> 11;
    int b = ch >> 9, d = ch & (DIm - 1);
    float As = -__expf(A_log[d * Ssz + lane]);
    float Dd = D_ssm[d];
    int base_m = b * Lseq + c * CHK;
    float dt_vec = dtmT[(size_t)d * (Bsz * Lseq) + base_m + lane];
    float x_vec  = xcT [(size_t)d * (Bsz * Lseq) + base_m + lane];
    float zown   = zT  [(size_t)d * (Bsz * Lseq) + base_m + lane];
    float ux = dt_vec * x_vec;
    const float* BCp = dbc2 + (size_t)base_m * 144 + 2 * lane;
    float h = Hinit[((size_t)ch * NCHK + c) * Ssz + lane];
    float yred = 0.0f;
    int tl = lane >> 2;
    int so = (lane & 3) * 16;
    for (int tb = 0; tb < 4; tb++) {
        #pragma unroll
        for (int j = 0; j < 16; j++) {
            int t = tb * 16 + j;
            float2 bc = *(const float2*)BCp; BCp += 144;
            float dtv = bcast(dt_vec, t);
            float u   = bcast(ux, t);
            float dA = __expf(dtv * As);
            h = fmaf(dA, h, u * bc.x);
            hCs[wid][j][lane] = h * bc.y;
        }
        const float* bp = &hCs[wid][tl][so];
        float4 a0 = *(const float4*)(bp + 0);
        float4 a1 = *(const float4*)(bp + 4);
        float4 a2 = *(const float4*)(bp + 8);
        float4 a3 = *(const float4*)(bp + 12);
        float part = ((a0.x + a0.y) + (a0.z + a0.w)) + ((a1.x + a1.y) + (a1.z + a1.w))
                   + ((a2.x + a2.y) + (a2.z + a2.w)) + ((a3.x + a3.y) + (a3.z + a3.w));
        part += __shfl_xor(part, 1, 64);
        part += __shfl_xor(part, 2, 64);
        float got = __shfl(part, ((lane - tb * 16) << 2) & 63, 64);
        if ((lane >> 4) == tb) yred = got;
    }
    float yg = (yred + x_vec * Dd) * (zown / (1.0f + __expf(-zown)));
    yTb[(size_t)d * (Bsz * Lseq) + base_m + lane] = (u16)f2bf(yg);
}

// ======= big4: o-GEMM (0-255) + outg (256-511) + gpre1 (512-767) + gpre2 (768-1023) =======
__global__ __launch_bounds__(256) void big4(const u16* __restrict__ attnb,
                                            const u16* __restrict__ yTb,
                                            const u16* __restrict__ wbf,
                                            const float* __restrict__ o_b,
                                            const float* __restrict__ c2,
                                            u16* __restrict__ cat2b,
                                            float* __restrict__ gpre1,
                                            float* __restrict__ gpre2) {
    __shared__ u16 As[64][40];
    __shared__ u16 Ws[64][40];
    int bx = blockIdx.x;
    int tid = threadIdx.x;
    int mode = bx >> 8;
    int l = bx & 255;
    int n0 = (l & 3) * 64, m0 = (l >> 2) * 64;
    int wave = tid >> 6, lane = tid & 63;
    int quad = lane >> 4, r = lane & 15;
    int mo = (wave >> 1) * 32, no = (wave & 1) * 32;
    f4v acc[2][2];
    #pragma unroll
    for (int i = 0; i < 2; i++)
        #pragma unroll
        for (int j = 0; j < 2; j++) acc[i][j] = (f4v){0.f, 0.f, 0.f, 0.f};
    if (mode == 0 || mode == 3) {
        const u16* W = (mode == 0) ? (wbf + WB_O) : (wbf + WB_W2P);
        mfma_core(attnb, 256, W, 256, m0, n0, 256, As, Ws, acc, tid);
        #pragma unroll
        for (int i = 0; i < 2; i++)
            #pragma unroll
            for (int j = 0; j < 2; j++)
                #pragma unroll
                for (int reg = 0; reg < 4; reg++) {
                    int m = m0 + mo + i * 16 + quad * 4 + reg;
                    int n = n0 + no + j * 16 + r;
                    if (mode == 0)
                        cat2b[(size_t)m * 512 + 256 + n] = (u16)f2bf(acc[i][j][reg] + o_b[n]);
                    else
                        gpre2[(size_t)m * 256 + n] = acc[i][j][reg] + c2[n];
                }
    } else {
        const u16* W = (mode == 1) ? (wbf + WB_OUT) : (wbf + WB_W1P);
        for (int k0 = 0; k0 < 512; k0 += 32) {
            {
                int k = tid >> 3, m8 = (tid & 7) * 8;
                s8v av = *(const s8v*)(yTb + (size_t)(k0 + k) * (Bsz * Lseq) + m0 + m8);
                #pragma unroll
                for (int i = 0; i < 8; i++) As[m8 + i][k] = (u16)av[i];
            }
            {
                int n = tid >> 2, kk = (tid & 3) * 8;
                *(s8v*)&Ws[n][kk] = *(const s8v*)(W + (size_t)(n0 + n) * 512 + k0 + kk);
            }
            __syncthreads();
            s8v af[2], bf[2];
            #pragma unroll
            for (int i = 0; i < 2; i++) af[i] = *(const s8v*)&As[mo + i * 16 + r][quad * 8];
            #pragma unroll
            for (int j = 0; j < 2; j++) bf[j] = *(const s8v*)&Ws[no + j * 16 + r][quad * 8];
            #pragma unroll
            for (int i = 0; i < 2; i++)
                #pragma unroll
                for (int j = 0; j < 2; j++)
                    acc[i][j] = __builtin_amdgcn_mfma_f32_16x16x32_bf16(af[i], bf[j], acc[i][j], 0, 0, 0);
            __syncthreads();
        }
        #pragma unroll
        for (int i = 0; i < 2; i++)
            #pragma unroll
            for (int j = 0; j < 2; j++)
                #pragma unroll
                for (int reg = 0; reg < 4; reg++) {
                    int m = m0 + mo + i * 16 + quad * 4 + reg;
                    int n = n0 + no + j * 16 + r;
                    if (mode == 1) cat2b[(size_t)m * 512 + n] = (u16)f2bf(acc[i][j][reg]);
                    else gpre1[(size_t)m * 256 + n] = acc[i][j][reg];
                }
    }
}

// ======= final: sigmoid gate + mix + residual =======
__global__ __launch_bounds__(256) void final_k(const float* __restrict__ gpre1,
                                               const float* __restrict__ gpre2,
                                               const float* __restrict__ gate_b,
                                               const u16* __restrict__ cat2b,
                                               const float* __restrict__ x,
                                               float* __restrict__ outp) {
    int idx4 = (blockIdx.x * 256 + threadIdx.x) * 4;
    int m = idx4 >> 8, n = idx4 & 255;
    float4 g1 = *(const float4*)(gpre1 + (size_t)m * 256 + n);
    float4 g2 = *(const float4*)(gpre2 + (size_t)m * 256 + n);
    float4 gb = *(const float4*)(gate_b + n);
    s4v sm = *(const s4v*)(cat2b + (size_t)m * 512 + n);
    s4v sd = *(const s4v*)(cat2b + (size_t)m * 512 + 256 + n);
    float4 xv = *(const float4*)(x + (size_t)m * 256 + n);
    float4 o;
    float gv[4] = {g1.x + g2.x + gb.x, g1.y + g2.y + gb.y,
                   g1.z + g2.z + gb.z, g1.w + g2.w + gb.w};
    float xr[4] = {xv.x, xv.y, xv.z, xv.w};
    float* op = (float*)&o;
    #pragma unroll
    for (int i = 0; i < 4; i++) {
        float gg = 1.0f / (1.0f + __expf(-gv[i]));
        float ssm = bf2f((u16)sm[i]);
        float ssd = bf2f((u16)sd[i]);
        op[i] = xr[i] + gg * ssm + (1.0f - gg) * ssd;
    }
    *(float4*)(outp + (size_t)m * 256 + n) = o;
}

extern "C" void kernel_launch(void* const* d_in, const int* in_sizes, int n_in,
                              void* d_out, int out_size, void* d_ws, size_t ws_size,
                              hipStream_t stream) {
    const float* x        = (const float*)d_in[0];
    const float* ln_g     = (const float*)d_in[1];
    const float* ln_b     = (const float*)d_in[2];
    const float* mq_w     = (const float*)d_in[3];
    const float* mq_b     = (const float*)d_in[4];
    const float* fuse_w   = (const float*)d_in[5];
    const float* fuse_b   = (const float*)d_in[6];
    const float* in_proj_w= (const float*)d_in[7];
    const float* conv_w   = (const float*)d_in[8];
    const float* conv_b   = (const float*)d_in[9];
    const float* x_proj_w = (const float*)d_in[10];
    const float* dt_w     = (const float*)d_in[11];
    const float* dt_b     = (const float*)d_in[12];
    const float* A_log    = (const float*)d_in[13];
    const float* D_ssm    = (const float*)d_in[14];
    const float* out_w    = (const float*)d_in[15];
    const float* k_w      = (const float*)d_in[16];
    const float* k_b      = (const float*)d_in[17];
    const float* v_w      = (const float*)d_in[18];
    const float* v_b      = (const float*)d_in[19];
    const float* o_w      = (const float*)d_in[20];
    const float* o_b      = (const float*)d_in[21];
    const float* log_tau  = (const float*)d_in[22];
    const float* gate_w   = (const float*)d_in[23];
    const float* gate_b   = (const float*)d_in[24];
    float* outp = (float*)d_out;

    const int M = Bsz * Lseq;
    float* ws = (float*)d_ws;
    size_t off = 0;
    float* zT    = ws + off; off += (size_t)DIm * M;
    float* xcT   = ws + off; off += (size_t)DIm * M;
    float* dtmT  = ws + off; off += (size_t)DIm * M;
    float* dbc2  = ws + off; off += (size_t)M * 144;
    float* qbuf  = ws + off; off += (size_t)M * Dm;
    float* kmat  = ws + off; off += (size_t)M * Dm;
    float* vmat  = ws + off; off += (size_t)M * Dm;
    float* loc   = ws + off; off += (size_t)64 * NCA * 512;
    float* hloc  = ws + off; off += (size_t)NCH * NCHK * Ssz;
    float* Pc    = ws + off; off += (size_t)NCH * NCHK * Ssz;
    float* kvtot = ws + off; off += (size_t)64 * 256;
    float* gpre1 = ws + off; off += (size_t)M * Dm;
    float* gpre2 = ws + off; off += (size_t)M * Dm;
    float* c2    = ws + off; off += 256;
    u16* ub = (u16*)(ws + off);
    size_t uo = 0;
    u16* xnb  = ub + uo; uo += (size_t)M * Dm;
    u16* xmb  = ub + uo; uo += (size_t)M * DIm;
    u16* xd2b = ub + uo; uo += (size_t)2048 * Dm;
    u16* xd4b = ub + uo; uo += (size_t)1024 * Dm;
    u16* xd8b = ub + uo; uo += (size_t)512 * Dm;
    u16* q0b  = ub + uo; uo += (size_t)M * Dm;
    u16* qd2b = ub + uo; uo += (size_t)2048 * Dm;
    u16* qd4b = ub + uo; uo += (size_t)1024 * Dm;
    u16* qd8b = ub + uo; uo += (size_t)512 * Dm;
    u16* attnb= ub + uo; uo += (size_t)M * Dm;
    u16* cat2b= ub + uo; uo += (size_t)M * 2 * Dm;
    u16* yTb  = ub + uo; uo += (size_t)DIm * M;
    u16* wbf  = ub + uo; uo += 1974272;
    u16* xcb  = cat2b;   // alias: conv bf16 output, dead before big4 writes cat2b

    // 1. LN + pooling + weight cvt + Wdt + out_wT + o_wT + c2
    ln_pool<<<1509, 256, 0, stream>>>(x, ln_g, ln_b, xnb, xd2b, xd4b, xd8b,
        in_proj_w, k_w, v_w, mq_w, fuse_w, x_proj_w, out_w, o_w, gate_w, dt_w, o_b, wbf, c2);

    // 2. projections + zT + W1' + W2'
    proj8<<<2064, 256, 0, stream>>>(xnb, xd2b, xd4b, xd8b, wbf,
        k_b, v_b, mq_b, xmb, zT, kmat, vmat, q0b, qd2b, qd4b, qd8b);

    // 3. fuse GEMM + conv/SiLU
    mid2<<<768, 256, 0, stream>>>(q0b, qd2b, qd4b, qd8b, wbf + WB_FUSE, fuse_b, qbuf,
        xmb, conv_w, conv_b, xcb, xcT);

    // 4. BC-GEMM (interleaved) + dt-GEMM + attn pass1
    xproj_ap1<<<1664, 256, 0, stream>>>(xcb, wbf, dbc2, dt_b, dtmT, kmat, vmat, log_tau, loc);

    // 5. scan pass1 + attn pass2
    sp1_ap2<<<8256, 256, 0, stream>>>(xcT, dtmT, dbc2, A_log, hloc, Pc, loc, log_tau, kvtot);

    // 6. chunk combine (in-place) + attn pass3
    comb_ap3<<<1536, 256, 0, stream>>>(hloc, Pc, qbuf, kmat, vmat, log_tau, loc, kvtot, attnb);

    // 7. scan pass3 (standalone, dwordx2 B/C loads)
    scan_pass3<<<8192, 256, 0, stream>>>(xcT, dtmT, zT, dbc2, A_log, D_ssm, hloc, yTb);

    // 8. o-GEMM + outg + gpre1 + gpre2 (all independent, one dispatch)
    big4<<<1024, 256, 0, stream>>>(attnb, yTb, wbf, o_b, c2, cat2b, gpre1, gpre2);

    // 9. sigmoid gate + mix + residual
    final_k<<<1024, 256, 0, stream>>>(gpre1, gpre2, gate_b, cat2b, x, outp);
}

// Round 15
// 293.083 us; speedup vs baseline: 1.1394x; 1.1394x over previous
//
#include <hip/hip_runtime.h>
#include <math.h>

#define Bsz 4
#define Lseq 1024
#define Dm 256
#define Hh 16
#define HDm 16
#define DIm 512
#define Ssz 64
#define KCm 4
#define DTRm 16
#define NCH (Bsz * DIm)
#define CHK 64
#define NCHK (Lseq / CHK)
#define CHA 16
#define NCA (Lseq / CHA)

typedef __attribute__((ext_vector_type(8))) short s8v;
typedef __attribute__((ext_vector_type(4))) short s4v;
typedef __attribute__((ext_vector_type(4))) float f4v;
typedef unsigned short u16;

static __device__ __forceinline__ float wave_sum(float v) {
    #pragma unroll
    for (int m = 32; m >= 1; m >>= 1) v += __shfl_xor(v, m, 64);
    return v;
}

static __device__ __forceinline__ float bcast(float v, int l) {
    return __uint_as_float(__builtin_amdgcn_readlane(__float_as_uint(v), l));
}

static __device__ __forceinline__ short f2bf(float f) {
    unsigned int u = __float_as_uint(f);
    u = (u + 0x7fffu + ((u >> 16) & 1u)) >> 16;
    return (short)u;
}

static __device__ __forceinline__ float bf2f(u16 u) {
    return __uint_as_float(((unsigned int)u) << 16);
}

static __device__ __forceinline__ s8v pack8(float4 a, float4 b) {
    s8v v;
    v[0] = f2bf(a.x); v[1] = f2bf(a.y); v[2] = f2bf(a.z); v[3] = f2bf(a.w);
    v[4] = f2bf(b.x); v[5] = f2bf(b.y); v[6] = f2bf(b.z); v[7] = f2bf(b.w);
    return v;
}

static __device__ __forceinline__ s4v pack4(float4 a) {
    s4v v;
    v[0] = f2bf(a.x); v[1] = f2bf(a.y); v[2] = f2bf(a.z); v[3] = f2bf(a.w);
    return v;
}

// ---- ln_pool: LayerNorm + 3-level pooling (blocks 0-511) + weight fp32->bf16 cvt (blocks 512-1155) ----
__global__ __launch_bounds__(256) void ln_pool(const float* __restrict__ x,
                                               const float* __restrict__ g,
                                               const float* __restrict__ bb,
                                               u16* __restrict__ xnb, u16* __restrict__ xd2b,
                                               u16* __restrict__ xd4b, u16* __restrict__ xd8b,
                                               const float* __restrict__ in_proj_w,
                                               const float* __restrict__ k_w,
                                               const float* __restrict__ v_w,
                                               const float* __restrict__ mq_w,
                                               const float* __restrict__ fuse_w,
                                               const float* __restrict__ x_proj_w,
                                               const float* __restrict__ out_w,
                                               const float* __restrict__ o_w,
                                               const float* __restrict__ gate_w,
                                               u16* __restrict__ wbf) {
    int bx = blockIdx.x;
    int tid = threadIdx.x;
    if (bx < 512) {
        __shared__ float p2[4][256];
        int wid = tid >> 6, lane = tid & 63;
        int gr0 = bx * 8;
        int b = gr0 >> 10, t0 = gr0 & 1023;
        float4 g4 = *(const float4*)(g + lane * 4);
        float4 b4 = *(const float4*)(bb + lane * 4);
        float4 res[2];
        #pragma unroll
        for (int rr = 0; rr < 2; rr++) {
            int row = gr0 + wid * 2 + rr;
            float4 xv = *(const float4*)(x + (size_t)row * 256 + lane * 4);
            float s = wave_sum(xv.x + xv.y + xv.z + xv.w);
            float mean = s * (1.0f / 256.0f);
            float d0 = xv.x - mean, d1 = xv.y - mean, d2 = xv.z - mean, d3 = xv.w - mean;
            float s2 = wave_sum(d0 * d0 + d1 * d1 + d2 * d2 + d3 * d3);
            float inv = rsqrtf(s2 * (1.0f / 256.0f) + 1e-5f);
            float4 r;
            r.x = d0 * inv * g4.x + b4.x; r.y = d1 * inv * g4.y + b4.y;
            r.z = d2 * inv * g4.z + b4.z; r.w = d3 * inv * g4.w + b4.w;
            *(s4v*)(xnb + (size_t)row * 256 + lane * 4) = pack4(r);
            res[rr] = r;
        }
        float4 a2;
        a2.x = 0.5f * (res[0].x + res[1].x); a2.y = 0.5f * (res[0].y + res[1].y);
        a2.z = 0.5f * (res[0].z + res[1].z); a2.w = 0.5f * (res[0].w + res[1].w);
        *(s4v*)(xd2b + (size_t)(b * 512 + (t0 >> 1) + wid) * 256 + lane * 4) = pack4(a2);
        *(float4*)&p2[wid][lane * 4] = a2;
        __syncthreads();
        if (wid < 2) {
            float4 u = *(const float4*)&p2[2 * wid][lane * 4];
            float4 w = *(const float4*)&p2[2 * wid + 1][lane * 4];
            float4 m;
            m.x = 0.5f * (u.x + w.x); m.y = 0.5f * (u.y + w.y);
            m.z = 0.5f * (u.z + w.z); m.w = 0.5f * (u.w + w.w);
            *(s4v*)(xd4b + (size_t)(b * 256 + (t0 >> 2) + wid) * 256 + lane * 4) = pack4(m);
        } else if (wid == 2) {
            float4 q0 = *(const float4*)&p2[0][lane * 4];
            float4 q1 = *(const float4*)&p2[1][lane * 4];
            float4 q2 = *(const float4*)&p2[2][lane * 4];
            float4 q3 = *(const float4*)&p2[3][lane * 4];
            float4 m;
            m.x = 0.25f * ((q0.x + q1.x) + (q2.x + q3.x));
            m.y = 0.25f * ((q0.y + q1.y) + (q2.y + q3.y));
            m.z = 0.25f * ((q0.z + q1.z) + (q2.z + q3.z));
            m.w = 0.25f * ((q0.w + q1.w) + (q2.w + q3.w));
            *(s4v*)(xd8b + (size_t)(b * 128 + (t0 >> 3)) * 256 + lane * 4) = pack4(m);
        }
    } else {
        int l = bx - 512;
        const float* src; u16* dst; int base;
        if (l < 128)      { src = in_proj_w; dst = wbf;           base = l; }
        else if (l < 160) { src = k_w;      dst = wbf + 262144;   base = l - 128; }
        else if (l < 192) { src = v_w;      dst = wbf + 327680;   base = l - 160; }
        else if (l < 320) { src = mq_w;     dst = wbf + 393216;   base = l - 192; }
        else if (l < 448) { src = fuse_w;   dst = wbf + 655360;   base = l - 320; }
        else if (l < 484) { src = x_proj_w; dst = wbf + 917504;   base = l - 448; }
        else if (l < 548) { src = out_w;    dst = wbf + 991232;   base = l - 484; }
        else if (l < 580) { src = o_w;      dst = wbf + 1122304;  base = l - 548; }
        else              { src = gate_w;   dst = wbf + 1187840;  base = l - 580; }
        int idx = base * 2048 + tid * 8;
        const float* sp = src + idx;
        *(s8v*)(dst + idx) = pack8(*(const float4*)sp, *(const float4*)(sp + 4));
    }
}

// ======= proj8: 8 K=256 projections, bf16 operands =======
__global__ __launch_bounds__(256) void proj8(const u16* __restrict__ xnb,
                                             const u16* __restrict__ xd2b,
                                             const u16* __restrict__ xd4b,
                                             const u16* __restrict__ xd8b,
                                             const u16* __restrict__ wbf,
                                             const float* __restrict__ k_b,
                                             const float* __restrict__ v_b,
                                             const float* __restrict__ mq_b,
                                             u16* __restrict__ xmb, float* __restrict__ zT,
                                             float* __restrict__ kmat, float* __restrict__ vmat,
                                             u16* __restrict__ q0b, u16* __restrict__ qd2b,
                                             u16* __restrict__ qd4b, u16* __restrict__ qd8b) {
    __shared__ u16 As[64][40];
    __shared__ u16 Ws[64][40];
    int bx = blockIdx.x;
    const u16* A; const u16* W; const float* bias;
    float* Cf = nullptr; u16* Cb = nullptr;
    int ldc, transC = 0, n0, m0;
    if (bx < 512) {
        A = xnb; W = wbf; bias = nullptr; Cb = xmb; ldc = DIm;
        n0 = (bx & 7) * 64; m0 = (bx >> 3) * 64;
    } else if (bx < 1024) {
        int l = bx - 512;
        A = xnb; W = wbf + 131072; bias = nullptr; Cf = zT; ldc = Bsz * Lseq; transC = 1;
        n0 = (l & 7) * 64; m0 = (l >> 3) * 64;
    } else if (bx < 1280) {
        int l = bx - 1024;
        A = xnb; W = wbf + 262144; bias = k_b; Cf = kmat; ldc = Dm;
        n0 = (l & 3) * 64; m0 = (l >> 2) * 64;
    } else if (bx < 1536) {
        int l = bx - 1280;
        A = xnb; W = wbf + 327680; bias = v_b; Cf = vmat; ldc = Dm;
        n0 = (l & 3) * 64; m0 = (l >> 2) * 64;
    } else if (bx < 1792) {
        int l = bx - 1536;
        A = xnb; W = wbf + 393216; bias = mq_b; Cb = q0b; ldc = Dm;
        n0 = (l & 3) * 64; m0 = (l >> 2) * 64;
    } else if (bx < 1920) {
        int l = bx - 1792;
        A = xd2b; W = wbf + 393216 + 65536; bias = mq_b + 256; Cb = qd2b; ldc = Dm;
        n0 = (l & 3) * 64; m0 = (l >> 2) * 64;
    } else if (bx < 1984) {
        int l = bx - 1920;
        A = xd4b; W = wbf + 393216 + 131072; bias = mq_b + 512; Cb = qd4b; ldc = Dm;
        n0 = (l & 3) * 64; m0 = (l >> 2) * 64;
    } else {
        int l = bx - 1984;
        A = xd8b; W = wbf + 393216 + 196608; bias = mq_b + 768; Cb = qd8b; ldc = Dm;
        n0 = (l & 3) * 64; m0 = (l >> 2) * 64;
    }
    int tid = threadIdx.x;
    int wave = tid >> 6, lane = tid & 63;
    int quad = lane >> 4, r = lane & 15;
    int mo = (wave >> 1) * 32, no = (wave & 1) * 32;
    f4v acc[2][2];
    #pragma unroll
    for (int i = 0; i < 2; i++)
        #pragma unroll
        for (int j = 0; j < 2; j++) acc[i][j] = (f4v){0.f, 0.f, 0.f, 0.f};
    for (int k0 = 0; k0 < 256; k0 += 32) {
        {
            int m = tid >> 2, kk = (tid & 3) * 8;
            *(s8v*)&As[m][kk] = *(const s8v*)(A + (size_t)(m0 + m) * 256 + k0 + kk);
        }
        {
            int n = tid >> 2, kk = (tid & 3) * 8;
            *(s8v*)&Ws[n][kk] = *(const s8v*)(W + (size_t)(n0 + n) * 256 + k0 + kk);
        }
        __syncthreads();
        s8v af[2], bf[2];
        #pragma unroll
        for (int i = 0; i < 2; i++) af[i] = *(const s8v*)&As[mo + i * 16 + r][quad * 8];
        #pragma unroll
        for (int j = 0; j < 2; j++) bf[j] = *(const s8v*)&Ws[no + j * 16 + r][quad * 8];
        #pragma unroll
        for (int i = 0; i < 2; i++)
            #pragma unroll
            for (int j = 0; j < 2; j++)
                acc[i][j] = __builtin_amdgcn_mfma_f32_16x16x32_bf16(af[i], bf[j], acc[i][j], 0, 0, 0);
        __syncthreads();
    }
    #pragma unroll
    for (int i = 0; i < 2; i++)
        #pragma unroll
        for (int j = 0; j < 2; j++)
            #pragma unroll
            for (int reg = 0; reg < 4; reg++) {
                int m = m0 + mo + i * 16 + quad * 4 + reg;
                int n = n0 + no + j * 16 + r;
                float v = acc[i][j][reg];
                if (bias) v += bias[n];
                if (Cb) Cb[(size_t)m * ldc + n] = (u16)f2bf(v);
                else {
                    float* cp = transC ? (Cf + (size_t)n * ldc + m) : (Cf + (size_t)m * ldc + n);
                    *cp = v;
                }
            }
}

// ======= mid2: fuse GEMM (blocks 0-255, on-the-fly interp, bf16) + conv+SiLU (blocks 256-767) =======
__global__ __launch_bounds__(256) void mid2(const u16* __restrict__ q0b,
                                            const u16* __restrict__ qd2b,
                                            const u16* __restrict__ qd4b,
                                            const u16* __restrict__ qd8b,
                                            const u16* __restrict__ w_fuse,
                                            const float* __restrict__ fuse_b,
                                            float* __restrict__ qbuf,
                                            const u16* __restrict__ xmb,
                                            const float* __restrict__ cw,
                                            const float* __restrict__ cb,
                                            u16* __restrict__ xcb, float* __restrict__ xcT) {
    __shared__ __align__(16) char smem[16640];
    int bx = blockIdx.x;
    int tid = threadIdx.x;
    if (bx < 256) {
        u16 (*As)[40] = (u16(*)[40])smem;
        u16 (*Ws)[40] = (u16(*)[40])(smem + 5120);
        int wave = tid >> 6, lane = tid & 63;
        int quad = lane >> 4, r = lane & 15;
        int n0 = (bx & 3) * 64, m0 = (bx >> 2) * 64;
        int mo = (wave >> 1) * 32, no = (wave & 1) * 32;
        f4v acc[2][2];
        #pragma unroll
        for (int i = 0; i < 2; i++)
            #pragma unroll
            for (int j = 0; j < 2; j++) acc[i][j] = (f4v){0.f, 0.f, 0.f, 0.f};
        for (int k0 = 0; k0 < 1024; k0 += 32) {
            {
                int m = tid >> 2, kk = (tid & 3) * 8;
                int kg = k0 + kk;
                int seg = kg >> 8, dcol = kg & 255;
                int mg = m0 + m;
                s8v pv;
                if (seg == 0) {
                    pv = *(const s8v*)(q0b + (size_t)mg * 256 + dcol);
                } else {
                    int t = mg & 1023, b = mg >> 10;
                    int Lin = 512 >> (seg - 1);
                    const u16* qd = (seg == 1) ? qd2b : (seg == 2) ? qd4b : qd8b;
                    float pos = (t + 0.5f) * ((float)Lin / 1024.0f) - 0.5f;
                    pos = fminf(fmaxf(pos, 0.0f), (float)(Lin - 1));
                    int lo = (int)floorf(pos);
                    int hi = min(lo + 1, Lin - 1);
                    float w = pos - (float)lo;
                    s8v lv = *(const s8v*)(qd + ((size_t)(b * Lin + lo)) * 256 + dcol);
                    s8v hv = *(const s8v*)(qd + ((size_t)(b * Lin + hi)) * 256 + dcol);
                    #pragma unroll
                    for (int i = 0; i < 8; i++) {
                        float lf = bf2f((u16)lv[i]), hf = bf2f((u16)hv[i]);
                        pv[i] = f2bf(lf + w * (hf - lf));
                    }
                }
                *(s8v*)&As[m][kk] = pv;
            }
            {
                int n = tid >> 2, kk = (tid & 3) * 8;
                *(s8v*)&Ws[n][kk] = *(const s8v*)(w_fuse + (size_t)(n0 + n) * 1024 + k0 + kk);
            }
            __syncthreads();
            s8v af[2], bf[2];
            #pragma unroll
            for (int i = 0; i < 2; i++) af[i] = *(const s8v*)&As[mo + i * 16 + r][quad * 8];
            #pragma unroll
            for (int j = 0; j < 2; j++) bf[j] = *(const s8v*)&Ws[no + j * 16 + r][quad * 8];
            #pragma unroll
            for (int i = 0; i < 2; i++)
                #pragma unroll
                for (int j = 0; j < 2; j++)
                    acc[i][j] = __builtin_amdgcn_mfma_f32_16x16x32_bf16(af[i], bf[j], acc[i][j], 0, 0, 0);
            __syncthreads();
        }
        #pragma unroll
        for (int i = 0; i < 2; i++)
            #pragma unroll
            for (int j = 0; j < 2; j++)
                #pragma unroll
                for (int reg = 0; reg < 4; reg++) {
                    int m = m0 + mo + i * 16 + quad * 4 + reg;
                    int n = n0 + no + j * 16 + r;
                    qbuf[(size_t)m * 256 + n] = acc[i][j][reg] + fuse_b[n];
                }
    } else {
        float (*tile)[65] = (float(*)[65])smem;
        int blk = bx - 256;
        int cblk = blk & 7;
        int tblk = (blk >> 3) & 15;
        int b = blk >> 7;
        int c0 = cblk * 64, t0 = tblk * 64;
        int cc = tid & 63;
        int tw = tid >> 6;
        int c = c0 + cc;
        float w0 = cw[c * 4 + 0], w1 = cw[c * 4 + 1], w2 = cw[c * 4 + 2], w3 = cw[c * 4 + 3];
        float bias = cb[c];
        #pragma unroll 4
        for (int i = 0; i < 16; i++) {
            int tl = tw * 16 + i;
            int t = t0 + tl;
            const u16* base = xmb + ((size_t)(b * Lseq + t)) * DIm + c;
            float acc = bias + bf2f(base[0]) * w3;
            if (t >= 3) {
                acc += bf2f(base[-3 * DIm]) * w0 + bf2f(base[-2 * DIm]) * w1 + bf2f(base[-1 * DIm]) * w2;
            } else {
                if (t >= 1) acc += bf2f(base[-1 * DIm]) * w2;
                if (t >= 2) acc += bf2f(base[-2 * DIm]) * w1;
            }
            float r = acc / (1.0f + __expf(-acc));
            xcb[((size_t)(b * Lseq + t)) * DIm + c] = (u16)f2bf(r);
            tile[tl][cc] = r;
        }
        __syncthreads();
        int tcol = tid & 63;
        int crow0 = tid >> 6;
        #pragma unroll 4
        for (int j = 0; j < 16; j++) {
            int crow = crow0 * 16 + j;
            xcT[((size_t)(c0 + crow)) * (Bsz * Lseq) + b * Lseq + t0 + tcol] = tile[tcol][crow];
        }
    }
}

// ======= xproj_ap1: x_proj GEMM (blocks 0-191, bf16) + attn pass1 (blocks 192-1215) =======
__global__ __launch_bounds__(256) void xproj_ap1(const u16* __restrict__ xcb,
                                                 const u16* __restrict__ w_xp,
                                                 float* __restrict__ dbc,
                                                 const float* __restrict__ kmat,
                                                 const float* __restrict__ vmat,
                                                 const float* __restrict__ log_tau,
                                                 float* __restrict__ loc) {
    __shared__ __align__(16) char smem[10240];
    int bx = blockIdx.x;
    int tid = threadIdx.x;
    int wid = tid >> 6, lane = tid & 63;
    if (bx < 192) {
        u16 (*As)[40] = (u16(*)[40])smem;
        u16 (*Ws)[40] = (u16(*)[40])(smem + 5120);
        int quad = lane >> 4, r = lane & 15;
        int n0 = (bx % 3) * 64, m0 = (bx / 3) * 64;
        int mo = (wid >> 1) * 32, no = (wid & 1) * 32;
        f4v acc[2][2];
        #pragma unroll
        for (int i = 0; i < 2; i++)
            #pragma unroll
            for (int j = 0; j < 2; j++) acc[i][j] = (f4v){0.f, 0.f, 0.f, 0.f};
        for (int k0 = 0; k0 < 512; k0 += 32) {
            {
                int m = tid >> 2, kk = (tid & 3) * 8;
                *(s8v*)&As[m][kk] = *(const s8v*)(xcb + (size_t)(m0 + m) * 512 + k0 + kk);
            }
            {
                int n = tid >> 2, kk = (tid & 3) * 8;
                s8v pv;
                if (n0 + n < 144) pv = *(const s8v*)(w_xp + (size_t)(n0 + n) * 512 + k0 + kk);
                else pv = (s8v){0, 0, 0, 0, 0, 0, 0, 0};
                *(s8v*)&Ws[n][kk] = pv;
            }
            __syncthreads();
            s8v af[2], bf[2];
            #pragma unroll
            for (int i = 0; i < 2; i++) af[i] = *(const s8v*)&As[mo + i * 16 + r][quad * 8];
            #pragma unroll
            for (int j = 0; j < 2; j++) bf[j] = *(const s8v*)&Ws[no + j * 16 + r][quad * 8];
            #pragma unroll
            for (int i = 0; i < 2; i++)
                #pragma unroll
                for (int j = 0; j < 2; j++)
                    acc[i][j] = __builtin_amdgcn_mfma_f32_16x16x32_bf16(af[i], bf[j], acc[i][j], 0, 0, 0);
            __syncthreads();
        }
        #pragma unroll
        for (int i = 0; i < 2; i++)
            #pragma unroll
            for (int j = 0; j < 2; j++)
                #pragma unroll
                for (int reg = 0; reg < 4; reg++) {
                    int m = m0 + mo + i * 16 + quad * 4 + reg;
                    int n = n0 + no + j * 16 + r;
                    if (n >= 144) continue;
                    dbc[(size_t)m * 144 + n] = acc[i][j][reg];
                }
    } else {
        float (*Ksh)[CHA][20] = (float(*)[CHA][20])smem;
        float (*Vsh)[CHA][16] = (float(*)[CHA][16])(smem + 5120);
        int wv = (bx - 192) * 4 + wid;
        int bh = wv >> 6, c = wv & 63;
        int b = bh >> 4, h = bh & 15;
        float inv_tau = __expf(-log_tau[h]);
        float rdec = __expf(-inv_tau);
        int t0 = c * CHA;
        int row = lane >> 2, q4 = (lane & 3) * 4;
        const float* kp = kmat + ((size_t)(b * Lseq + t0 + row)) * Dm + h * HDm + q4;
        const float* vp = vmat + ((size_t)(b * Lseq + t0 + row)) * Dm + h * HDm + q4;
        *(float4*)&Ksh[wid][row][q4] = *(const float4*)kp;
        *(float4*)&Vsh[wid][row][q4] = *(const float4*)vp;
        int g = lane >> 4, cc = lane & 15;
        float4 U = {0.f, 0.f, 0.f, 0.f}, T = {0.f, 0.f, 0.f, 0.f};
        #pragma unroll
        for (int s = 0; s < CHA; s++) {
            float4 kf = *(const float4*)&Ksh[wid][s][4 * g];
            float vv = Vsh[wid][s][cc];
            float u0 = kf.x * vv, u1 = kf.y * vv, u2 = kf.z * vv, u3 = kf.w * vv;
            U.x += u0; U.y += u1; U.z += u2; U.w += u3;
            T.x = fmaf(rdec, T.x, u0); T.y = fmaf(rdec, T.y, u1);
            T.z = fmaf(rdec, T.z, u2); T.w = fmaf(rdec, T.w, u3);
        }
        float* op = loc + ((size_t)bh * NCA + c) * 512;
        *(float4*)(op + lane * 4) = U;
        *(float4*)(op + 256 + lane * 4) = T;
    }
}

// ======= dt_ap2: dt GEMM+softplus (blocks 0-511) + attn pass2 in-place scan (blocks 512-575) =======
__global__ __launch_bounds__(256) void dt_ap2(const float* __restrict__ dbc,
                                              const float* __restrict__ dt_w,
                                              const float* __restrict__ dt_b,
                                              float* __restrict__ dtmT,
                                              float* __restrict__ loc,
                                              const float* __restrict__ log_tau,
                                              float* __restrict__ kvtot) {
    __shared__ __align__(16) char smem[9216];
    int bx = blockIdx.x;
    int tid = threadIdx.x;
    if (bx < 512) {
        float (*As)[72] = (float(*)[72])smem;
        float (*Ws)[72] = (float(*)[72])(smem + 4608);
        int m0 = (bx >> 3) * 64, n0 = (bx & 7) * 64;
        int tx = tid & 15, ty = tid >> 4;
        float acc[4][4] = {};
        {
            int ml = tid >> 2, kl = (tid & 3) * 4;
            const float4 av = *(const float4*)(dbc + (size_t)(m0 + ml) * 144 + kl);
            As[kl + 0][ml] = av.x; As[kl + 1][ml] = av.y;
            As[kl + 2][ml] = av.z; As[kl + 3][ml] = av.w;
        }
        {
            int nl = tid >> 2, kl = (tid & 3) * 4;
            float4 wv = *(const float4*)(dt_w + (size_t)(n0 + nl) * 16 + kl);
            Ws[kl + 0][nl] = wv.x; Ws[kl + 1][nl] = wv.y;
            Ws[kl + 2][nl] = wv.z; Ws[kl + 3][nl] = wv.w;
        }
        __syncthreads();
        #pragma unroll
        for (int kk = 0; kk < 16; kk++) {
            float4 av = *(const float4*)&As[kk][ty * 4];
            float4 bv = *(const float4*)&Ws[kk][tx * 4];
            float a[4] = {av.x, av.y, av.z, av.w};
            float bbv[4] = {bv.x, bv.y, bv.z, bv.w};
            #pragma unroll
            for (int im = 0; im < 4; im++)
                #pragma unroll
                for (int in = 0; in < 4; in++)
                    acc[im][in] = fmaf(a[im], bbv[in], acc[im][in]);
        }
        #pragma unroll
        for (int in = 0; in < 4; in++) {
            int n = n0 + tx * 4 + in;
            #pragma unroll
            for (int im = 0; im < 4; im++) {
                int m = m0 + ty * 4 + im;
                float v = acc[im][in] + dt_b[n];
                v = fmaxf(v, 0.0f) + log1pf(expf(-fabsf(v)));
                dtmT[(size_t)n * (Bsz * Lseq) + m] = v;
            }
        }
    } else {
        int bh = bx - 512, e = tid;
        float inv_tau = __expf(-log_tau[bh & 15]);
        float rp = __expf(-(float)CHA * inv_tau);
        float* lp = loc + (size_t)bh * NCA * 512;
        float Ua = 0.f, Ta = 0.f;
        #pragma unroll 8
        for (int c = 0; c < NCA; c++) {
            float tu = lp[c * 512 + e];
            lp[c * 512 + e] = Ua;
            Ua += tu;
            float tt = lp[c * 512 + 256 + e];
            lp[c * 512 + 256 + e] = Ta;
            Ta = fmaf(rp, Ta, tt);
        }
        kvtot[bh * 256 + e] = Ua;
    }
}

// ======= sp1_ap3: scan pass1 (blocks 0-8191) + attn pass3 (blocks 8192-9215, bf16 out) =======
__global__ __launch_bounds__(256) void sp1_ap3(const float* __restrict__ xcT,
                                               const float* __restrict__ dtmT,
                                               const float* __restrict__ dbc,
                                               const float* __restrict__ A_log,
                                               float* __restrict__ hloc,
                                               float* __restrict__ Pc,
                                               const float* __restrict__ q,
                                               const float* __restrict__ kmat,
                                               const float* __restrict__ vmat,
                                               const float* __restrict__ log_tau,
                                               const float* __restrict__ init,
                                               const float* __restrict__ kvtot,
                                               u16* __restrict__ attnb) {
    __shared__ __align__(16) char smem[18432];
    int bx = blockIdx.x;
    int tid = threadIdx.x;
    int wid = tid >> 6, lane = tid & 63;
    if (bx < 8192) {
        int wave = bx * 4 + wid;
        int ch = wave & (NCH - 1);
        int c  = wave >> 11;
        int b = ch >> 9, d = ch & (DIm - 1);
        float As = -__expf(A_log[d * Ssz + lane]);
        int base_m = b * Lseq + c * CHK;
        float dt_vec = dtmT[(size_t)d * (Bsz * Lseq) + base_m + lane];
        float x_vec  = xcT [(size_t)d * (Bsz * Lseq) + base_m + lane];
        float ux = dt_vec * x_vec;
        float S = dt_vec;
        #pragma unroll
        for (int m = 1; m < 64; m <<= 1) {
            float o = __shfl_up(S, m, 64);
            if (lane >= m) S += o;
        }
        float Stot = bcast(S, 63);
        const float* Bp = dbc + (size_t)base_m * 144 + DTRm + lane;
        float h0 = 0.f, h1 = 0.f, h2 = 0.f, h3 = 0.f;
        #pragma unroll 4
        for (int t = 0; t < CHK; t += 4) {
            float B0 = Bp[0], B1 = Bp[144], B2 = Bp[288], B3 = Bp[432];
            Bp += 576;
            float w0 = __expf(As * (Stot - bcast(S, t)))     * bcast(ux, t);
            float w1 = __expf(As * (Stot - bcast(S, t + 1))) * bcast(ux, t + 1);
            float w2 = __expf(As * (Stot - bcast(S, t + 2))) * bcast(ux, t + 2);
            float w3 = __expf(As * (Stot - bcast(S, t + 3))) * bcast(ux, t + 3);
            h0 = fmaf(w0, B0, h0); h1 = fmaf(w1, B1, h1);
            h2 = fmaf(w2, B2, h2); h3 = fmaf(w3, B3, h3);
        }
        size_t o = ((size_t)ch * NCHK + c) * Ssz + lane;
        hloc[o] = (h0 + h1) + (h2 + h3);
        Pc[o] = __expf(As * Stot);
    } else {
        float (*Ksh)[CHA][20] = (float(*)[CHA][20])smem;
        float (*Qsh)[CHA][20] = (float(*)[CHA][20])(smem + 5120);
        float (*Vsh)[CHA][16] = (float(*)[CHA][16])(smem + 10240);
        float (*Ysh)[CHA][16] = (float(*)[CHA][16])(smem + 14336);
        int wv = (bx - 8192) * 4 + wid;
        int bh = wv >> 6, c = wv & 63;
        int b = bh >> 4, h = bh & 15;
        float inv_tau = __expf(-log_tau[h]);
        float rdec = __expf(-inv_tau);
        int t0 = c * CHA;
        int row = lane >> 2, q4 = (lane & 3) * 4;
        const float* kp = kmat + ((size_t)(b * Lseq + t0 + row)) * Dm + h * HDm + q4;
        const float* vp = vmat + ((size_t)(b * Lseq + t0 + row)) * Dm + h * HDm + q4;
        const float* qp = q    + ((size_t)(b * Lseq + t0 + row)) * Dm + h * HDm + q4;
        *(float4*)&Ksh[wid][row][q4] = *(const float4*)kp;
        *(float4*)&Vsh[wid][row][q4] = *(const float4*)vp;
        *(float4*)&Qsh[wid][row][q4] = *(const float4*)qp;
        int g = lane >> 4, cc = lane & 15;
        size_t ibase = ((size_t)bh * NCA + c) * 512;
        float4 U  = *(const float4*)(init + ibase + lane * 4);
        float4 T  = *(const float4*)(init + ibase + 256 + lane * 4);
        float4 KV = *(const float4*)(kvtot + bh * 256 + lane * 4);
        float om = 1.0f - rdec;
        float geom = (om > 1e-8f) ? (1.0f - __expf(-inv_tau * (float)t0)) / om : (float)t0;
        #pragma unroll
        for (int s = 0; s < CHA; s++) {
            int i = t0 + s;
            geom = fmaf(geom, rdec, 1.0f);
            float4 kf = *(const float4*)&Ksh[wid][s][4 * g];
            float4 qf = *(const float4*)&Qsh[wid][s][4 * g];
            float vv = Vsh[wid][s][cc];
            float u0 = kf.x * vv, u1 = kf.y * vv, u2 = kf.z * vv, u3 = kf.w * vv;
            U.x += u0; U.y += u1; U.z += u2; U.w += u3;
            T.x = fmaf(rdec, T.x, u0); T.y = fmaf(rdec, T.y, u1);
            T.z = fmaf(rdec, T.z, u2); T.w = fmaf(rdec, T.w, u3);
            float p;
            p = qf.x * (KV.x - U.x + T.x);
            p = fmaf(qf.y, KV.y - U.y + T.y, p);
            p = fmaf(qf.z, KV.z - U.z + T.z, p);
            p = fmaf(qf.w, KV.w - U.w + T.w, p);
            p += __shfl_xor(p, 16, 64);
            p += __shfl_xor(p, 32, 64);
            float deno = fmaxf((float)(Lseq - 1 - i) + geom, 1e-6f);
            float yv = p * (0.25f / deno);
            if (lane < 16) Ysh[wid][s][lane] = yv;
        }
        float4 yv4 = *(const float4*)&Ysh[wid][row][q4];
        *(s4v*)(attnb + ((size_t)(b * Lseq + t0 + row)) * Dm + h * HDm + q4) = pack4(yv4);
    }
}

// ======= comb_ssd: in-place chunk combine (blocks 0-511) + ssd o-GEMM (blocks 512-767) =======
__global__ __launch_bounds__(256) void comb_ssd(float* __restrict__ hloc,
                                                const float* __restrict__ Pc,
                                                const u16* __restrict__ attnb,
                                                const u16* __restrict__ w_o,
                                                const float* __restrict__ o_b,
                                                u16* __restrict__ cat2b) {
    __shared__ u16 As[64][40];
    __shared__ u16 Ws[64][40];
    int bx = blockIdx.x;
    int tid = threadIdx.x;
    if (bx < 512) {
        int wave = bx * 4 + (tid >> 6);
        int lane = tid & 63;
        size_t base = (size_t)wave * NCHK * Ssz + lane;
        float H = 0.0f;
        #pragma unroll
        for (int c = 0; c < NCHK; c++) {
            size_t o = base + (size_t)c * Ssz;
            float p = Pc[o];
            float hl = hloc[o];
            hloc[o] = H;
            H = fmaf(p, H, hl);
        }
    } else {
        int l = bx - 512;
        int wave = tid >> 6, lane = tid & 63;
        int quad = lane >> 4, r = lane & 15;
        int n0 = (l & 3) * 64, m0 = (l >> 2) * 64;
        int mo = (wave >> 1) * 32, no = (wave & 1) * 32;
        f4v acc[2][2];
        #pragma unroll
        for (int i = 0; i < 2; i++)
            #pragma unroll
            for (int j = 0; j < 2; j++) acc[i][j] = (f4v){0.f, 0.f, 0.f, 0.f};
        for (int k0 = 0; k0 < 256; k0 += 32) {
            {
                int m = tid >> 2, kk = (tid & 3) * 8;
                *(s8v*)&As[m][kk] = *(const s8v*)(attnb + (size_t)(m0 + m) * 256 + k0 + kk);
            }
            {
                int n = tid >> 2, kk = (tid & 3) * 8;
                *(s8v*)&Ws[n][kk] = *(const s8v*)(w_o + (size_t)(n0 + n) * 256 + k0 + kk);
            }
            __syncthreads();
            s8v af[2], bf[2];
            #pragma unroll
            for (int i = 0; i < 2; i++) af[i] = *(const s8v*)&As[mo + i * 16 + r][quad * 8];
            #pragma unroll
            for (int j = 0; j < 2; j++) bf[j] = *(const s8v*)&Ws[no + j * 16 + r][quad * 8];
            #pragma unroll
            for (int i = 0; i < 2; i++)
                #pragma unroll
                for (int j = 0; j < 2; j++)
                    acc[i][j] = __builtin_amdgcn_mfma_f32_16x16x32_bf16(af[i], bf[j], acc[i][j], 0, 0, 0);
            __syncthreads();
        }
        #pragma unroll
        for (int i = 0; i < 2; i++)
            #pragma unroll
            for (int j = 0; j < 2; j++)
                #pragma unroll
                for (int reg = 0; reg < 4; reg++) {
                    int m = m0 + mo + i * 16 + quad * 4 + reg;
                    int n = n0 + no + j * 16 + r;
                    cat2b[(size_t)m * 512 + 256 + n] = (u16)f2bf(acc[i][j][reg] + o_b[n]);
                }
    }
}

__global__ __launch_bounds__(256) void scan_pass3(const float* __restrict__ xcT,
                                                  const float* __restrict__ dtmT,
                                                  const float* __restrict__ zT,
                                                  const float* __restrict__ dbc,
                                                  const float* __restrict__ A_log,
                                                  const float* __restrict__ D_ssm,
                                                  const float* __restrict__ Hinit,
                                                  u16* __restrict__ yTb) {
    __shared__ float hCs[4][16][68];
    int wid = threadIdx.x >> 6;
    int lane = threadIdx.x & 63;
    int wave = blockIdx.x * 4 + wid;
    int ch = wave & (NCH - 1);
    int c  = wave >> 11;
    int b = ch >> 9, d = ch & (DIm - 1);
    float As = -__expf(A_log[d * Ssz + lane]);
    float Dd = D_ssm[d];
    int base_m = b * Lseq + c * CHK;
    float dt_vec = dtmT[(size_t)d * (Bsz * Lseq) + base_m + lane];
    float x_vec  = xcT [(size_t)d * (Bsz * Lseq) + base_m + lane];
    float zown   = zT  [(size_t)d * (Bsz * Lseq) + base_m + lane];
    float ux = dt_vec * x_vec;
    const float* Bp = dbc + (size_t)base_m * 144 + DTRm + lane;
    const float* Cp = Bp + Ssz;
    float h = Hinit[((size_t)ch * NCHK + c) * Ssz + lane];
    float yred = 0.0f;
    int tl = lane >> 2;
    int so = (lane & 3) * 16;
    for (int tb = 0; tb < 4; tb++) {
        #pragma unroll
        for (int j = 0; j < 16; j++) {
            int t = tb * 16 + j;
            float Bt = *Bp; Bp += 144;
            float Ct = *Cp; Cp += 144;
            float dtv = bcast(dt_vec, t);
            float u   = bcast(ux, t);
            float dA = __expf(dtv * As);
            h = fmaf(dA, h, u * Bt);
            hCs[wid][j][lane] = h * Ct;
        }
        const float* bp = &hCs[wid][tl][so];
        float4 a0 = *(const float4*)(bp + 0);
        float4 a1 = *(const float4*)(bp + 4);
        float4 a2 = *(const float4*)(bp + 8);
        float4 a3 = *(const float4*)(bp + 12);
        float part = ((a0.x + a0.y) + (a0.z + a0.w)) + ((a1.x + a1.y) + (a1.z + a1.w))
                   + ((a2.x + a2.y) + (a2.z + a2.w)) + ((a3.x + a3.y) + (a3.z + a3.w));
        part += __shfl_xor(part, 1, 64);
        part += __shfl_xor(part, 2, 64);
        float got = __shfl(part, ((lane - tb * 16) << 2) & 63, 64);
        if ((lane >> 4) == tb) yred = got;
    }
    float yg = (yred + x_vec * Dd) * (zown / (1.0f + __expf(-zown)));
    yTb[(size_t)d * (Bsz * Lseq) + base_m + lane] = (u16)f2bf(yg);
}

// ======= outg: out-GEMM yT^T @ out_w^T -> cat2 ssm half (256 blocks) =======
__global__ __launch_bounds__(256) void outg(const u16* __restrict__ yTb,
                                            const u16* __restrict__ w_out,
                                            u16* __restrict__ cat2b) {
    __shared__ u16 As[64][40];
    __shared__ u16 Ws[64][40];
    int bx = blockIdx.x;
    int tid = threadIdx.x;
    int wave = tid >> 6, lane = tid & 63;
    int quad = lane >> 4, r = lane & 15;
    int n0 = (bx & 3) * 64, m0 = (bx >> 2) * 64;
    int mo = (wave >> 1) * 32, no = (wave & 1) * 32;
    f4v acc[2][2];
    #pragma unroll
    for (int i = 0; i < 2; i++)
        #pragma unroll
        for (int j = 0; j < 2; j++) acc[i][j] = (f4v){0.f, 0.f, 0.f, 0.f};
    for (int k0 = 0; k0 < 512; k0 += 32) {
        {
            int k = tid >> 3, m8 = (tid & 7) * 8;
            s8v av = *(const s8v*)(yTb + (size_t)(k0 + k) * (Bsz * Lseq) + m0 + m8);
            #pragma unroll
            for (int i = 0; i < 8; i++) As[m8 + i][k] = (u16)av[i];
        }
        {
            int n = tid >> 2, kk = (tid & 3) * 8;
            *(s8v*)&Ws[n][kk] = *(const s8v*)(w_out + (size_t)(n0 + n) * 512 + k0 + kk);
        }
        __syncthreads();
        s8v af[2], bf[2];
        #pragma unroll
        for (int i = 0; i < 2; i++) af[i] = *(const s8v*)&As[mo + i * 16 + r][quad * 8];
        #pragma unroll
        for (int j = 0; j < 2; j++) bf[j] = *(const s8v*)&Ws[no + j * 16 + r][quad * 8];
        #pragma unroll
        for (int i = 0; i < 2; i++)
            #pragma unroll
            for (int j = 0; j < 2; j++)
                acc[i][j] = __builtin_amdgcn_mfma_f32_16x16x32_bf16(af[i], bf[j], acc[i][j], 0, 0, 0);
        __syncthreads();
    }
    #pragma unroll
    for (int i = 0; i < 2; i++)
        #pragma unroll
        for (int j = 0; j < 2; j++)
            #pragma unroll
            for (int reg = 0; reg < 4; reg++) {
                int m = m0 + mo + i * 16 + quad * 4 + reg;
                int n = n0 + no + j * 16 + r;
                cat2b[(size_t)m * 512 + n] = (u16)f2bf(acc[i][j][reg]);
            }
}

// ======= gate GEMM (K=512, bf16) with fused sigmoid-gate + residual epilogue =======
__global__ __launch_bounds__(256) void gate_gemm(const u16* __restrict__ cat2b,
                                                 const u16* __restrict__ w_gate,
                                                 const float* __restrict__ gate_b,
                                                 const float* __restrict__ xres,
                                                 float* __restrict__ fout) {
    __shared__ u16 As[64][40];
    __shared__ u16 Ws[64][40];
    int tid = threadIdx.x;
    int wave = tid >> 6, lane = tid & 63;
    int quad = lane >> 4, r = lane & 15;
    int m0 = blockIdx.y * 64, n0 = blockIdx.x * 64;
    int mo = (wave >> 1) * 32, no = (wave & 1) * 32;
    f4v acc[2][2];
    #pragma unroll
    for (int i = 0; i < 2; i++)
        #pragma unroll
        for (int j = 0; j < 2; j++) acc[i][j] = (f4v){0.f, 0.f, 0.f, 0.f};
    for (int k0 = 0; k0 < 512; k0 += 32) {
        {
            int m = tid >> 2, kk = (tid & 3) * 8;
            *(s8v*)&As[m][kk] = *(const s8v*)(cat2b + (size_t)(m0 + m) * 512 + k0 + kk);
        }
        {
            int n = tid >> 2, kk = (tid & 3) * 8;
            *(s8v*)&Ws[n][kk] = *(const s8v*)(w_gate + (size_t)(n0 + n) * 512 + k0 + kk);
        }
        __syncthreads();
        s8v af[2], bf[2];
        #pragma unroll
        for (int i = 0; i < 2; i++) af[i] = *(const s8v*)&As[mo + i * 16 + r][quad * 8];
        #pragma unroll
        for (int j = 0; j < 2; j++) bf[j] = *(const s8v*)&Ws[no + j * 16 + r][quad * 8];
        #pragma unroll
        for (int i = 0; i < 2; i++)
            #pragma unroll
            for (int j = 0; j < 2; j++)
                acc[i][j] = __builtin_amdgcn_mfma_f32_16x16x32_bf16(af[i], bf[j], acc[i][j], 0, 0, 0);
        __syncthreads();
    }
    #pragma unroll
    for (int i = 0; i < 2; i++)
        #pragma unroll
        for (int j = 0; j < 2; j++)
            #pragma unroll
            for (int reg = 0; reg < 4; reg++) {
                int m = m0 + mo + i * 16 + quad * 4 + reg;
                int n = n0 + no + j * 16 + r;
                float v = acc[i][j][reg] + gate_b[n];
                float gg = 1.0f / (1.0f + __expf(-v));
                float ssm = bf2f(cat2b[(size_t)m * 512 + n]);
                float ssd = bf2f(cat2b[(size_t)m * 512 + 256 + n]);
                fout[(size_t)m * 256 + n] = xres[(size_t)m * 256 + n] + gg * ssm + (1.0f - gg) * ssd;
            }
}

extern "C" void kernel_launch(void* const* d_in, const int* in_sizes, int n_in,
                              void* d_out, int out_size, void* d_ws, size_t ws_size,
                              hipStream_t stream) {
    const float* x        = (const float*)d_in[0];
    const float* ln_g     = (const float*)d_in[1];
    const float* ln_b     = (const float*)d_in[2];
    const float* mq_w     = (const float*)d_in[3];
    const float* mq_b     = (const float*)d_in[4];
    const float* fuse_w   = (const float*)d_in[5];
    const float* fuse_b   = (const float*)d_in[6];
    const float* in_proj_w= (const float*)d_in[7];
    const float* conv_w   = (const float*)d_in[8];
    const float* conv_b   = (const float*)d_in[9];
    const float* x_proj_w = (const float*)d_in[10];
    const float* dt_w     = (const float*)d_in[11];
    const float* dt_b     = (const float*)d_in[12];
    const float* A_log    = (const float*)d_in[13];
    const float* D_ssm    = (const float*)d_in[14];
    const float* out_w    = (const float*)d_in[15];
    const float* k_w      = (const float*)d_in[16];
    const float* k_b      = (const float*)d_in[17];
    const float* v_w      = (const float*)d_in[18];
    const float* v_b      = (const float*)d_in[19];
    const float* o_w      = (const float*)d_in[20];
    const float* o_b      = (const float*)d_in[21];
    const float* log_tau  = (const float*)d_in[22];
    const float* gate_w   = (const float*)d_in[23];
    const float* gate_b   = (const float*)d_in[24];
    float* outp = (float*)d_out;

    const int M = Bsz * Lseq;
    float* ws = (float*)d_ws;
    size_t off = 0;
    float* zT    = ws + off; off += (size_t)DIm * M;
    float* xcT   = ws + off; off += (size_t)DIm * M;
    float* dtmT  = ws + off; off += (size_t)DIm * M;
    float* dbc   = ws + off; off += (size_t)M * 144;
    float* qbuf  = ws + off; off += (size_t)M * Dm;
    float* kmat  = ws + off; off += (size_t)M * Dm;
    float* vmat  = ws + off; off += (size_t)M * Dm;
    float* loc   = ws + off; off += (size_t)64 * NCA * 512;
    float* hloc  = ws + off; off += (size_t)NCH * NCHK * Ssz;
    float* Pc    = ws + off; off += (size_t)NCH * NCHK * Ssz;
    float* kvtot = ws + off; off += (size_t)64 * 256;
    u16* ub = (u16*)(ws + off);
    size_t uo = 0;
    u16* xnb  = ub + uo; uo += (size_t)M * Dm;
    u16* xmb  = ub + uo; uo += (size_t)M * DIm;
    u16* xd2b = ub + uo; uo += (size_t)2048 * Dm;
    u16* xd4b = ub + uo; uo += (size_t)1024 * Dm;
    u16* xd8b = ub + uo; uo += (size_t)512 * Dm;
    u16* q0b  = ub + uo; uo += (size_t)M * Dm;
    u16* qd2b = ub + uo; uo += (size_t)2048 * Dm;
    u16* qd4b = ub + uo; uo += (size_t)1024 * Dm;
    u16* qd8b = ub + uo; uo += (size_t)512 * Dm;
    u16* attnb= ub + uo; uo += (size_t)M * Dm;
    u16* cat2b= ub + uo; uo += (size_t)M * 2 * Dm;
    u16* yTb  = ub + uo; uo += (size_t)DIm * M;
    u16* wbf  = ub + uo; uo += 1318912;
    u16* xcb  = cat2b;   // alias: conv's row-major bf16 output, dead before comb_ssd writes cat2b

    // 1. LN + pooling + weight conversion (one dispatch)
    ln_pool<<<1156, 256, 0, stream>>>(x, ln_g, ln_b, xnb, xd2b, xd4b, xd8b,
        in_proj_w, k_w, v_w, mq_w, fuse_w, x_proj_w, out_w, o_w, gate_w, wbf);

    // 2. all K=256 projections (bf16)
    proj8<<<2016, 256, 0, stream>>>(xnb, xd2b, xd4b, xd8b, wbf,
        k_b, v_b, mq_b, xmb, zT, kmat, vmat, q0b, qd2b, qd4b, qd8b);

    // 3. fuse GEMM + conv/SiLU
    mid2<<<768, 256, 0, stream>>>(q0b, qd2b, qd4b, qd8b, wbf + 655360, fuse_b, qbuf,
        xmb, conv_w, conv_b, xcb, xcT);

    // 4. x_proj GEMM + attn pass1
    xproj_ap1<<<1216, 256, 0, stream>>>(xcb, wbf + 917504, dbc, kmat, vmat, log_tau, loc);

    // 5. dt GEMM + attn pass2 (in-place)
    dt_ap2<<<576, 256, 0, stream>>>(dbc, dt_w, dt_b, dtmT, loc, log_tau, kvtot);

    // 6. scan pass1 + attn pass3
    sp1_ap3<<<9216, 256, 0, stream>>>(xcT, dtmT, dbc, A_log, hloc, Pc,
        qbuf, kmat, vmat, log_tau, loc, kvtot, attnb);

    // 7. chunk combine (in-place) + ssd o-GEMM (overlapped)
    comb_ssd<<<768, 256, 0, stream>>>(hloc, Pc, attnb, wbf + 1122304, o_b, cat2b);

    // 8. scan pass3 (yT as bf16)
    scan_pass3<<<8192, 256, 0, stream>>>(xcT, dtmT, zT, dbc, A_log, D_ssm, hloc, yTb);

    // 9. out-GEMM -> cat2 ssm half
    outg<<<256, 256, 0, stream>>>(yTb, wbf + 991232, cat2b);

    // 10. gate GEMM with fused sigmoid-gate + residual -> d_out
    gate_gemm<<<dim3(4, 64), 256, 0, stream>>>(cat2b, wbf + 1187840, gate_b, x, outp);
}